// Round 5
// baseline (927.420 us; speedup 1.0000x reference)
//
#include <hip/hip_runtime.h>
#include <hip/hip_bf16.h>

// Reservoir ESN forward. Key tricks:
//  1. Wres entries are {0, 0.02} exactly -> compress to 12.6MB bitmask once per
//     call; per-step GEMM expands bits->bf16{0,1} and uses MFMA, x0.02 at finish.
//  2. The "a = coef*sum|h|" scalar cancels exactly in the global LayerNorm
//     (uniform additive shift) -> dropped entirely.
//  3. LN(h_prev)+leaky is fused into the GEMM's LDS A-staging (needs only the
//     2 accumulated stats scalars of the previous step).
//  4. Wres-compress (HBM-bound ~63us) fused with f_in GEMM (VALU-bound ~19us)
//     in one kernel so they overlap; t=0 stats fused there too.
//  5. h_new written in-place into fin[t]; final LN fused into classifier.

typedef short short8 __attribute__((ext_vector_type(8)));
typedef float f32x4 __attribute__((ext_vector_type(4)));
typedef unsigned int u32x4 __attribute__((ext_vector_type(4)));

#define NB 16            // batch
#define MR 10000         // reservoir size
#define KCOL 10240       // padded K/col stride (fp32 elems), 320 ksteps * 32
#define IPAD 10112       // padded output-i rows (79 blocks * 128)
#define BMROW 1280       // bitmask row stride in bytes (10240 bits)
#define NELEM 160000.0f  // 16*10000 elements for LN stats
#define NFIN 480         // fin blocks in k_front (40 colblocks x 12 t)

// ---------------- block reduce (sum, sumsq) -> atomicAdd slot ----------------
__device__ __forceinline__ void block_reduce_add2(float s, float q, float* slot) {
  #pragma unroll
  for (int d = 32; d > 0; d >>= 1) {
    s += __shfl_down(s, d, 64);
    q += __shfl_down(q, d, 64);
  }
  __shared__ float ls[8], lq[8];
  int w = threadIdx.x >> 6;
  if ((threadIdx.x & 63) == 0) { ls[w] = s; lq[w] = q; }
  __syncthreads();
  if (threadIdx.x == 0) {
    float S = 0.f, Q = 0.f;
    int nw = blockDim.x >> 6;
    for (int k = 0; k < nw; ++k) { S += ls[k]; Q += lq[k]; }
    atomicAdd(&slot[0], S);
    atomicAdd(&slot[1], Q);
  }
}

// ------------- fused front kernel: fin blocks [0,480) + compress -------------
// Byte layout within each bitmask row is swizzled so the GEMM can load 8
// ksteps of bits per lane-group with one dwordx2:
//   phys = 64*(jb>>6) | 16*(jb&3) | ((jb>>2)&15)   (bijective bit-field perm)
__global__ __launch_bounds__(256) void k_front(const float* __restrict__ Wres,
                                               const float* __restrict__ fs,
                                               const float* __restrict__ Win,
                                               unsigned char* __restrict__ bm,
                                               float* __restrict__ fin,
                                               float* __restrict__ slots) {
  int bx = blockIdx.x;
  int tid = threadIdx.x;
  if (bx < NFIN) {
    // ---- f_in[t] = fs[t] @ Win (fp32). XCD-contiguous column mapping so each
    // XCD re-reads only a ~3.9MB slice of Win across its 12 t-blocks (L2-fit).
    int xcd = bx & 7, s = bx >> 3;
    int t = s % 12, cb = xcd * 5 + s / 12;    // cb in [0,40)
    int i0 = cb * 256 + tid;                  // col 0..10239
    float* dst = fin + (size_t)t * (NB * KCOL) + i0;
    float acc[NB];
    #pragma unroll
    for (int b = 0; b < NB; ++b) acc[b] = 0.f;
    bool pad = (i0 >= MR);
    if (pad) {
      #pragma unroll
      for (int b = 0; b < NB; ++b) dst[b * KCOL] = 0.f;
    } else {
      const float* fsr = fs + t * (NB * 768);  // block-uniform -> s_load
      #pragma unroll 4
      for (int k = 0; k < 768; ++k) {
        float w = Win[(size_t)k * MR + i0];
        #pragma unroll
        for (int b = 0; b < NB; ++b) acc[b] += fsr[b * 768 + k] * w;
      }
      #pragma unroll
      for (int b = 0; b < NB; ++b) dst[b * KCOL] = acc[b];
    }
    if (t == 0) {  // h_new(0) == f_in[0] (h0 = 0) -> LN stats now
      float sm = 0.f, sq = 0.f;
      if (!pad) {
        #pragma unroll
        for (int b = 0; b < NB; ++b) { sm += acc[b]; sq += acc[b] * acc[b]; }
      }
      block_reduce_add2(sm, sq, slots);       // slot 0 (zeroed by memset)
    }
    return;
  }
  // ---- Wres row -> 1280 swizzled bitmask bytes (rows >= MR and j >= MR -> 0)
  int i = bx - NFIN;                          // row 0..10111
  #pragma unroll
  for (int m = 0; m < 5; ++m) {
    int jb = tid + 256 * m;                   // logical byte 0..1279
    unsigned int b = 0;
    if (i < MR && jb < 1250) {                // j in [8*jb, 8*jb+8) < 10000
      const float* src = Wres + (size_t)i * MR + jb * 8;
      float4 v0 = *(const float4*)(src);
      float4 v1 = *(const float4*)(src + 4);
      b  = (v0.x != 0.f ? 1u : 0u);
      b |= (v0.y != 0.f ? 2u : 0u);
      b |= (v0.z != 0.f ? 4u : 0u);
      b |= (v0.w != 0.f ? 8u : 0u);
      b |= (v1.x != 0.f ? 16u : 0u);
      b |= (v1.y != 0.f ? 32u : 0u);
      b |= (v1.z != 0.f ? 64u : 0u);
      b |= (v1.w != 0.f ? 128u : 0u);
    }
    int phys = ((jb >> 6) << 6) | ((jb & 3) << 4) | ((jb >> 2) & 15);
    bm[(size_t)i * BMROW + phys] = (unsigned char)b;
  }
}

// ------------- bit pair -> packed bf16 pair (1.0/0.0), compile-safe ----------
__device__ __forceinline__ unsigned int pair_bf16(unsigned int w, int bit) {
  // (w>>bit)&1 -> 0x3F80 low half; (w>>(bit+1))&1 -> 0x3F80 high half
  int m0 = ((int)(w << (31 - bit))) >> 31;        // v_bfe_i32 pattern
  int m1 = ((int)(w << (30 - bit))) >> 31;
  return ((unsigned)m0 & 0x3F80u) | ((unsigned)m1 & 0x3F800000u);
}
__device__ __forceinline__ short8 expand8(unsigned int w, int bitbase) {
  union { unsigned int u[4]; short8 s; } r;
  #pragma unroll
  for (int p = 0; p < 4; ++p) r.u[p] = pair_bf16(w, bitbase + 2 * p);
  return r.s;
}

// ---- per-step GEMM: part[ksp] = hnorm(prev) @ Bbits^T chunk (bf16 MFMA) -----
// grid 632 = 79 i-blocks x 8 K-chunks, XCD-swizzled so an XCD owns ~10
// consecutive i-blocks (bitmask slice ~1.6MB -> L2-resident across 11 steps).
__global__ __launch_bounds__(256) void k_gemm(const float* __restrict__ hsrc,
                                              const float* __restrict__ slot,
                                              const unsigned char* __restrict__ bm,
                                              float* __restrict__ part) {
  __shared__ unsigned int Alds[16 * 644];     // 16 rows x 1288 bf16 (conflict pad)
  int n = blockIdx.x;
  int id = (n & 7) * 79 + (n >> 3);
  int ib = id >> 3, ksp = id & 7;             // ib 0..78, ksp 0..7
  int tid = threadIdx.x;
  float mu = slot[0] * (1.f / NELEM);
  float var = slot[1] * (1.f / NELEM) - mu * mu;
  float rs = rsqrtf(var + 1e-5f);
  float murs = mu * rs;
  {
    // stage A chunk [16][1280]: LN + leaky + bf16 pack, fused
    int row = tid >> 4, jj = tid & 15;
    const float* hrow = hsrc + row * KCOL + ksp * 1280;
    unsigned int* lrow = Alds + row * 644;
    #pragma unroll 4
    for (int it = 0; it < 40; ++it) {
      int jp = jj + 16 * it;
      float2 v = *(const float2*)(hrow + 2 * jp);
      float x0 = fmaf(v.x, rs, -murs); x0 = (x0 >= 0.f) ? x0 : 0.01f * x0;
      float x1 = fmaf(v.y, rs, -murs); x1 = (x1 >= 0.f) ? x1 : 0.01f * x1;
      unsigned int pk;
      asm("v_cvt_pk_bf16_f32 %0, %1, %2" : "=v"(pk) : "v"(x0), "v"(x1));
      lrow[jp] = pk;
    }
  }
  __syncthreads();
  int wave = tid >> 6, lane = tid & 63;
  int r = lane & 15, q = lane >> 4;
  int i0 = ib * 128 + wave * 32;              // wave owns 2 N-tiles (32 i)
  const unsigned int* ab = Alds + r * 644 + q * 4;
  const unsigned char* b0p = bm + (size_t)(i0 + r) * BMROW;
  f32x4 acc0 = {0.f, 0.f, 0.f, 0.f}, acc1 = {0.f, 0.f, 0.f, 0.f};
  for (int g = 0; g < 5; ++g) {               // 5 x 8 = 40 ksteps of 32
    int sg = 5 * ksp + g;
    int off = ((sg >> 1) << 6) + (q << 4) + ((sg & 1) << 3);
    uint2 w0 = *(const uint2*)(b0p + off);
    uint2 w1 = *(const uint2*)(b0p + 16 * BMROW + off);
    #pragma unroll
    for (int e8 = 0; e8 < 8; ++e8) {
      int ksl = g * 8 + e8;
      union { u32x4 v; short8 s; } a;
      a.v = *(const u32x4*)(ab + ksl * 16);   // ds_read_b128
      unsigned int wb0 = (e8 < 4) ? w0.x : w0.y;
      unsigned int wb1 = (e8 < 4) ? w1.x : w1.y;
      int bb = (e8 & 3) * 8;
      acc0 = __builtin_amdgcn_mfma_f32_16x16x32_bf16(a.s, expand8(wb0, bb), acc0, 0, 0, 0);
      acc1 = __builtin_amdgcn_mfma_f32_16x16x32_bf16(a.s, expand8(wb1, bb), acc1, 0, 0, 0);
    }
  }
  // D layout: col = lane&15 (= i), row = (lane>>4)*4+reg (= batch)
  float* pp = part + (size_t)ksp * (NB * IPAD) + (q * 4) * IPAD + i0 + r;
  #pragma unroll
  for (int rg = 0; rg < 4; ++rg) {
    pp[rg * IPAD] = acc0[rg];
    pp[rg * IPAD + 16] = acc1[rg];
  }
}

// -- h_new = f_in + 0.02*sum(partials), IN-PLACE into fin[t]; stats -> slot ---
__global__ __launch_bounds__(256) void k_finish(const float* __restrict__ part,
                                                float* __restrict__ finio,
                                                float* __restrict__ slot) {
  int u = blockIdx.x * 256 + threadIdx.x;
  float s = 0.f, q = 0.f;
  if (u < 40000) {
    int b = u / 2500, i = (u % 2500) * 4;
    size_t o = (size_t)b * IPAD + i;
    float4 p = *(const float4*)(part + o);
    #pragma unroll
    for (int sp = 1; sp < 8; ++sp) {
      float4 t = *(const float4*)(part + (size_t)sp * (NB * IPAD) + o);
      p.x += t.x; p.y += t.y; p.z += t.z; p.w += t.w;
    }
    float* fp = finio + (size_t)b * KCOL + i;
    float4 f = *(const float4*)(fp);
    float4 h;
    h.x = fmaf(0.02f, p.x, f.x);
    h.y = fmaf(0.02f, p.y, f.y);
    h.z = fmaf(0.02f, p.z, f.z);
    h.w = fmaf(0.02f, p.w, f.w);
    *(float4*)(fp) = h;
    s = h.x + h.y + h.z + h.w;
    q = h.x * h.x + h.y * h.y + h.z * h.z + h.w * h.w;
  }
  block_reduce_add2(s, q, slot);
}

// ------ out = LN(h11) @ Wout (16 x 200, K=10000, split-K, LN fused in) ------
__global__ __launch_bounds__(256) void k_classify(const float* __restrict__ hraw,
                                                  const float* __restrict__ slot,
                                                  const float* __restrict__ Wout,
                                                  float* __restrict__ out) {
  int cg = blockIdx.x % 25, ksp = blockIdx.x / 25;
  int tid = threadIdx.x;
  int kp = tid >> 3, cl = tid & 7;    // 32 k-slices x 8 classes
  int c = cg * 8 + cl;
  int kbase = ksp * 1280;
  int kend = min(kbase + 1280, MR);
  float mu = slot[0] * (1.f / NELEM);
  float var = slot[1] * (1.f / NELEM) - mu * mu;
  float rs = rsqrtf(var + 1e-5f);
  float murs = mu * rs;
  float acc[NB];
  #pragma unroll
  for (int b = 0; b < NB; ++b) acc[b] = 0.f;
  for (int k = kbase + kp; k < kend; k += 32) {
    float w = Wout[(size_t)k * 200 + c];
    #pragma unroll
    for (int b = 0; b < NB; ++b) {
      float x = fmaf(hraw[(size_t)b * KCOL + k], rs, -murs);
      x = (x >= 0.f) ? x : 0.01f * x;
      acc[b] = fmaf(x, w, acc[b]);
    }
  }
  #pragma unroll
  for (int d = 8; d < 64; d <<= 1) {
    #pragma unroll
    for (int b = 0; b < NB; ++b) acc[b] += __shfl_down(acc[b], d, 64);
  }
  __shared__ float lds[4 * 128];
  int w = tid >> 6, lane = tid & 63;
  if (lane < 8) {
    #pragma unroll
    for (int b = 0; b < NB; ++b) lds[w * 128 + lane * 16 + b] = acc[b];
  }
  __syncthreads();
  if (tid < 128) {
    int clx = tid >> 4, b = tid & 15;
    float S = lds[clx * 16 + b] + lds[128 + clx * 16 + b] +
              lds[256 + clx * 16 + b] + lds[384 + clx * 16 + b];
    atomicAdd(&out[b * 200 + cg * 8 + clx], S);
  }
}

extern "C" void kernel_launch(void* const* d_in, const int* in_sizes, int n_in,
                              void* d_out, int out_size, void* d_ws, size_t ws_size,
                              hipStream_t stream) {
  const float* fs   = (const float*)d_in[0];
  const float* Win  = (const float*)d_in[1];
  const float* Wres = (const float*)d_in[2];
  const float* Wout = (const float*)d_in[3];
  float* out = (float*)d_out;
  char* ws = (char*)d_ws;

  // workspace layout (~26.0 MB)
  size_t off_bm   = 256;
  size_t off_fin  = off_bm + (size_t)IPAD * BMROW;
  size_t off_part = off_fin + (size_t)12 * NB * KCOL * 4;
  size_t need     = off_part + (size_t)8 * NB * IPAD * 4;
  if (ws_size < need) return;   // defensive: never write OOB scratch

  float* slots = (float*)ws;                     // 24 floats used
  unsigned char* bm = (unsigned char*)(ws + off_bm);
  float* fin = (float*)(ws + off_fin);
  float* part = (float*)(ws + off_part);

  hipMemsetAsync(slots, 0, 256, stream);
  hipMemsetAsync(out, 0, (size_t)NB * 200 * sizeof(float), stream);

  k_front<<<NFIN + IPAD, 256, 0, stream>>>(Wres, fs, Win, bm, fin, slots);

  // fin[t] holds f_in[t]; after k_finish(t) it holds h_new(t) in place.
  for (int t = 1; t < 12; ++t) {
    k_gemm<<<632, 256, 0, stream>>>(fin + (size_t)(t - 1) * NB * KCOL,
                                    slots + 2 * (t - 1), bm, part);
    k_finish<<<157, 256, 0, stream>>>(part, fin + (size_t)t * NB * KCOL,
                                      slots + 2 * t);
  }
  k_classify<<<200, 256, 0, stream>>>(fin + (size_t)11 * NB * KCOL,
                                      slots + 22, Wout, out);
}

// Round 6
// 925.527 us; speedup vs baseline: 1.0020x; 1.0020x over previous
//
#include <hip/hip_runtime.h>
#include <hip/hip_bf16.h>

// Reservoir ESN forward. Key tricks:
//  1. Wres entries are {0, 0.02} exactly -> compress to 12.6MB bitmask once per
//     call; per-step GEMM expands bits->bf16{0,1} and uses MFMA, x0.02 at finish.
//  2. The "a = coef*sum|h|" scalar cancels exactly in the global LayerNorm
//     (uniform additive shift) -> dropped entirely.
//  3. LN(h_prev)+leaky is fused into the GEMM's LDS A-staging (needs only the
//     2 accumulated stats scalars of the previous step).
//  4. Wres-compress (HBM-bound ~63us) fused with f_in GEMM (VALU-bound ~19us)
//     in one kernel so they overlap; t=0 stats fused there too.
//  5. h_new written in-place into fin[t]; final LN fused into classifier.
//  6. (R5) bit->bf16 pair expansion via bfe + 2x v_mul_u32_u24 (5 VALU/pair,
//     bit-identical output) instead of sign-extend+mask (7 VALU/pair).

typedef short short8 __attribute__((ext_vector_type(8)));
typedef float f32x4 __attribute__((ext_vector_type(4)));
typedef unsigned int u32x4 __attribute__((ext_vector_type(4)));

#define NB 16            // batch
#define MR 10000         // reservoir size
#define KCOL 10240       // padded K/col stride (fp32 elems), 320 ksteps * 32
#define IPAD 10112       // padded output-i rows (79 blocks * 128)
#define BMROW 1280       // bitmask row stride in bytes (10240 bits)
#define NELEM 160000.0f  // 16*10000 elements for LN stats
#define NFIN 480         // fin blocks in k_front (40 colblocks x 12 t)

// ---------------- block reduce (sum, sumsq) -> atomicAdd slot ----------------
__device__ __forceinline__ void block_reduce_add2(float s, float q, float* slot) {
  #pragma unroll
  for (int d = 32; d > 0; d >>= 1) {
    s += __shfl_down(s, d, 64);
    q += __shfl_down(q, d, 64);
  }
  __shared__ float ls[8], lq[8];
  int w = threadIdx.x >> 6;
  if ((threadIdx.x & 63) == 0) { ls[w] = s; lq[w] = q; }
  __syncthreads();
  if (threadIdx.x == 0) {
    float S = 0.f, Q = 0.f;
    int nw = blockDim.x >> 6;
    for (int k = 0; k < nw; ++k) { S += ls[k]; Q += lq[k]; }
    atomicAdd(&slot[0], S);
    atomicAdd(&slot[1], Q);
  }
}

// ------------- fused front kernel: fin blocks [0,480) + compress -------------
// Byte layout within each bitmask row is swizzled so the GEMM can load 8
// ksteps of bits per lane-group with one dwordx2:
//   phys = 64*(jb>>6) | 16*(jb&3) | ((jb>>2)&15)   (bijective bit-field perm)
__global__ __launch_bounds__(256) void k_front(const float* __restrict__ Wres,
                                               const float* __restrict__ fs,
                                               const float* __restrict__ Win,
                                               unsigned char* __restrict__ bm,
                                               float* __restrict__ fin,
                                               float* __restrict__ slots) {
  int bx = blockIdx.x;
  int tid = threadIdx.x;
  if (bx < NFIN) {
    // ---- f_in[t] = fs[t] @ Win (fp32). XCD-contiguous column mapping so each
    // XCD re-reads only a ~3.9MB slice of Win across its 12 t-blocks (L2-fit).
    int xcd = bx & 7, s = bx >> 3;
    int t = s % 12, cb = xcd * 5 + s / 12;    // cb in [0,40)
    int i0 = cb * 256 + tid;                  // col 0..10239
    float* dst = fin + (size_t)t * (NB * KCOL) + i0;
    float acc[NB];
    #pragma unroll
    for (int b = 0; b < NB; ++b) acc[b] = 0.f;
    bool pad = (i0 >= MR);
    if (pad) {
      #pragma unroll
      for (int b = 0; b < NB; ++b) dst[b * KCOL] = 0.f;
    } else {
      const float* fsr = fs + t * (NB * 768);  // block-uniform -> s_load
      #pragma unroll 4
      for (int k = 0; k < 768; ++k) {
        float w = Win[(size_t)k * MR + i0];
        #pragma unroll
        for (int b = 0; b < NB; ++b) acc[b] += fsr[b * 768 + k] * w;
      }
      #pragma unroll
      for (int b = 0; b < NB; ++b) dst[b * KCOL] = acc[b];
    }
    if (t == 0) {  // h_new(0) == f_in[0] (h0 = 0) -> LN stats now
      float sm = 0.f, sq = 0.f;
      if (!pad) {
        #pragma unroll
        for (int b = 0; b < NB; ++b) { sm += acc[b]; sq += acc[b] * acc[b]; }
      }
      block_reduce_add2(sm, sq, slots);       // slot 0 (zeroed by memset)
    }
    return;
  }
  // ---- Wres row -> 1280 swizzled bitmask bytes (rows >= MR and j >= MR -> 0)
  int i = bx - NFIN;                          // row 0..10111
  #pragma unroll
  for (int m = 0; m < 5; ++m) {
    int jb = tid + 256 * m;                   // logical byte 0..1279
    unsigned int b = 0;
    if (i < MR && jb < 1250) {                // j in [8*jb, 8*jb+8) < 10000
      const float* src = Wres + (size_t)i * MR + jb * 8;
      float4 v0 = *(const float4*)(src);
      float4 v1 = *(const float4*)(src + 4);
      b  = (v0.x != 0.f ? 1u : 0u);
      b |= (v0.y != 0.f ? 2u : 0u);
      b |= (v0.z != 0.f ? 4u : 0u);
      b |= (v0.w != 0.f ? 8u : 0u);
      b |= (v1.x != 0.f ? 16u : 0u);
      b |= (v1.y != 0.f ? 32u : 0u);
      b |= (v1.z != 0.f ? 64u : 0u);
      b |= (v1.w != 0.f ? 128u : 0u);
    }
    int phys = ((jb >> 6) << 6) | ((jb & 3) << 4) | ((jb >> 2) & 15);
    bm[(size_t)i * BMROW + phys] = (unsigned char)b;
  }
}

// ---- bit pair -> packed bf16 pair (1.0/0.0), 5 full-rate VALU, bit-exact ----
// t = (b_{bit+1}:b_bit); t*0x8001 & 0x10001 puts b_bit at pos0, b_{bit+1} at
// pos16; *0x3F80 turns each into bf16 1.0 in its half. Muls pinned to
// v_mul_u32_u24 (VOP2, literal-in-src0 legal; all operands < 2^24).
__device__ __forceinline__ unsigned int pair_bf16(unsigned int w, int bit) {
  unsigned int t = (w << (30 - bit)) >> 30;   // 2-bit extract (v_bfe_u32)
  unsigned int m, u;
  asm("v_mul_u32_u24 %0, 0x8001, %1" : "=v"(m) : "v"(t));
  m &= 0x00010001u;
  asm("v_mul_u32_u24 %0, 0x3f80, %1" : "=v"(u) : "v"(m));
  return u;
}
__device__ __forceinline__ short8 expand8(unsigned int w, int bitbase) {
  union { unsigned int u[4]; short8 s; } r;
  #pragma unroll
  for (int p = 0; p < 4; ++p) r.u[p] = pair_bf16(w, bitbase + 2 * p);
  return r.s;
}

// ---- per-step GEMM: part[ksp] = hnorm(prev) @ Bbits^T chunk (bf16 MFMA) -----
// grid 632 = 79 i-blocks x 8 K-chunks, XCD-swizzled so an XCD owns ~10
// consecutive i-blocks (bitmask slice ~1.6MB -> L2-resident across 11 steps).
__global__ __launch_bounds__(256) void k_gemm(const float* __restrict__ hsrc,
                                              const float* __restrict__ slot,
                                              const unsigned char* __restrict__ bm,
                                              float* __restrict__ part) {
  __shared__ unsigned int Alds[16 * 644];     // 16 rows x 1288 bf16 (conflict pad)
  int n = blockIdx.x;
  int id = (n & 7) * 79 + (n >> 3);
  int ib = id >> 3, ksp = id & 7;             // ib 0..78, ksp 0..7
  int tid = threadIdx.x;
  float mu = slot[0] * (1.f / NELEM);
  float var = slot[1] * (1.f / NELEM) - mu * mu;
  float rs = rsqrtf(var + 1e-5f);
  float murs = mu * rs;
  {
    // stage A chunk [16][1280]: LN + leaky + bf16 pack, fused
    int row = tid >> 4, jj = tid & 15;
    const float* hrow = hsrc + row * KCOL + ksp * 1280;
    unsigned int* lrow = Alds + row * 644;
    #pragma unroll 4
    for (int it = 0; it < 40; ++it) {
      int jp = jj + 16 * it;
      float2 v = *(const float2*)(hrow + 2 * jp);
      float x0 = fmaf(v.x, rs, -murs); x0 = (x0 >= 0.f) ? x0 : 0.01f * x0;
      float x1 = fmaf(v.y, rs, -murs); x1 = (x1 >= 0.f) ? x1 : 0.01f * x1;
      unsigned int pk;
      asm("v_cvt_pk_bf16_f32 %0, %1, %2" : "=v"(pk) : "v"(x0), "v"(x1));
      lrow[jp] = pk;
    }
  }
  __syncthreads();
  int wave = tid >> 6, lane = tid & 63;
  int r = lane & 15, q = lane >> 4;
  int i0 = ib * 128 + wave * 32;              // wave owns 2 N-tiles (32 i)
  const unsigned int* ab = Alds + r * 644 + q * 4;
  const unsigned char* b0p = bm + (size_t)(i0 + r) * BMROW;
  f32x4 acc0 = {0.f, 0.f, 0.f, 0.f}, acc1 = {0.f, 0.f, 0.f, 0.f};
  for (int g = 0; g < 5; ++g) {               // 5 x 8 = 40 ksteps of 32
    int sg = 5 * ksp + g;
    int off = ((sg >> 1) << 6) + (q << 4) + ((sg & 1) << 3);
    uint2 w0 = *(const uint2*)(b0p + off);
    uint2 w1 = *(const uint2*)(b0p + 16 * BMROW + off);
    #pragma unroll
    for (int e8 = 0; e8 < 8; ++e8) {
      int ksl = g * 8 + e8;
      union { u32x4 v; short8 s; } a;
      a.v = *(const u32x4*)(ab + ksl * 16);   // ds_read_b128
      unsigned int wb0 = (e8 < 4) ? w0.x : w0.y;
      unsigned int wb1 = (e8 < 4) ? w1.x : w1.y;
      int bb = (e8 & 3) * 8;
      acc0 = __builtin_amdgcn_mfma_f32_16x16x32_bf16(a.s, expand8(wb0, bb), acc0, 0, 0, 0);
      acc1 = __builtin_amdgcn_mfma_f32_16x16x32_bf16(a.s, expand8(wb1, bb), acc1, 0, 0, 0);
    }
  }
  // D layout: col = lane&15 (= i), row = (lane>>4)*4+reg (= batch)
  float* pp = part + (size_t)ksp * (NB * IPAD) + (q * 4) * IPAD + i0 + r;
  #pragma unroll
  for (int rg = 0; rg < 4; ++rg) {
    pp[rg * IPAD] = acc0[rg];
    pp[rg * IPAD + 16] = acc1[rg];
  }
}

// -- h_new = f_in + 0.02*sum(partials), IN-PLACE into fin[t]; stats -> slot ---
__global__ __launch_bounds__(256) void k_finish(const float* __restrict__ part,
                                                float* __restrict__ finio,
                                                float* __restrict__ slot) {
  int u = blockIdx.x * 256 + threadIdx.x;
  float s = 0.f, q = 0.f;
  if (u < 40000) {
    int b = u / 2500, i = (u % 2500) * 4;
    size_t o = (size_t)b * IPAD + i;
    float4 p = *(const float4*)(part + o);
    #pragma unroll
    for (int sp = 1; sp < 8; ++sp) {
      float4 t = *(const float4*)(part + (size_t)sp * (NB * IPAD) + o);
      p.x += t.x; p.y += t.y; p.z += t.z; p.w += t.w;
    }
    float* fp = finio + (size_t)b * KCOL + i;
    float4 f = *(const float4*)(fp);
    float4 h;
    h.x = fmaf(0.02f, p.x, f.x);
    h.y = fmaf(0.02f, p.y, f.y);
    h.z = fmaf(0.02f, p.z, f.z);
    h.w = fmaf(0.02f, p.w, f.w);
    *(float4*)(fp) = h;
    s = h.x + h.y + h.z + h.w;
    q = h.x * h.x + h.y * h.y + h.z * h.z + h.w * h.w;
  }
  block_reduce_add2(s, q, slot);
}

// ------ out = LN(h11) @ Wout (16 x 200, K=10000, split-K, LN fused in) ------
__global__ __launch_bounds__(256) void k_classify(const float* __restrict__ hraw,
                                                  const float* __restrict__ slot,
                                                  const float* __restrict__ Wout,
                                                  float* __restrict__ out) {
  int cg = blockIdx.x % 25, ksp = blockIdx.x / 25;
  int tid = threadIdx.x;
  int kp = tid >> 3, cl = tid & 7;    // 32 k-slices x 8 classes
  int c = cg * 8 + cl;
  int kbase = ksp * 1280;
  int kend = min(kbase + 1280, MR);
  float mu = slot[0] * (1.f / NELEM);
  float var = slot[1] * (1.f / NELEM) - mu * mu;
  float rs = rsqrtf(var + 1e-5f);
  float murs = mu * rs;
  float acc[NB];
  #pragma unroll
  for (int b = 0; b < NB; ++b) acc[b] = 0.f;
  for (int k = kbase + kp; k < kend; k += 32) {
    float w = Wout[(size_t)k * 200 + c];
    #pragma unroll
    for (int b = 0; b < NB; ++b) {
      float x = fmaf(hraw[(size_t)b * KCOL + k], rs, -murs);
      x = (x >= 0.f) ? x : 0.01f * x;
      acc[b] = fmaf(x, w, acc[b]);
    }
  }
  #pragma unroll
  for (int d = 8; d < 64; d <<= 1) {
    #pragma unroll
    for (int b = 0; b < NB; ++b) acc[b] += __shfl_down(acc[b], d, 64);
  }
  __shared__ float lds[4 * 128];
  int w = tid >> 6, lane = tid & 63;
  if (lane < 8) {
    #pragma unroll
    for (int b = 0; b < NB; ++b) lds[w * 128 + lane * 16 + b] = acc[b];
  }
  __syncthreads();
  if (tid < 128) {
    int clx = tid >> 4, b = tid & 15;
    float S = lds[clx * 16 + b] + lds[128 + clx * 16 + b] +
              lds[256 + clx * 16 + b] + lds[384 + clx * 16 + b];
    atomicAdd(&out[b * 200 + cg * 8 + clx], S);
  }
}

extern "C" void kernel_launch(void* const* d_in, const int* in_sizes, int n_in,
                              void* d_out, int out_size, void* d_ws, size_t ws_size,
                              hipStream_t stream) {
  const float* fs   = (const float*)d_in[0];
  const float* Win  = (const float*)d_in[1];
  const float* Wres = (const float*)d_in[2];
  const float* Wout = (const float*)d_in[3];
  float* out = (float*)d_out;
  char* ws = (char*)d_ws;

  // workspace layout (~26.0 MB)
  size_t off_bm   = 256;
  size_t off_fin  = off_bm + (size_t)IPAD * BMROW;
  size_t off_part = off_fin + (size_t)12 * NB * KCOL * 4;
  size_t need     = off_part + (size_t)8 * NB * IPAD * 4;
  if (ws_size < need) return;   // defensive: never write OOB scratch

  float* slots = (float*)ws;                     // 24 floats used
  unsigned char* bm = (unsigned char*)(ws + off_bm);
  float* fin = (float*)(ws + off_fin);
  float* part = (float*)(ws + off_part);

  hipMemsetAsync(slots, 0, 256, stream);
  hipMemsetAsync(out, 0, (size_t)NB * 200 * sizeof(float), stream);

  k_front<<<NFIN + IPAD, 256, 0, stream>>>(Wres, fs, Win, bm, fin, slots);

  // fin[t] holds f_in[t]; after k_finish(t) it holds h_new(t) in place.
  for (int t = 1; t < 12; ++t) {
    k_gemm<<<632, 256, 0, stream>>>(fin + (size_t)(t - 1) * NB * KCOL,
                                    slots + 2 * (t - 1), bm, part);
    k_finish<<<157, 256, 0, stream>>>(part, fin + (size_t)t * NB * KCOL,
                                      slots + 2 * t);
  }
  k_classify<<<200, 256, 0, stream>>>(fin + (size_t)11 * NB * KCOL,
                                      slots + 22, Wout, out);
}